// Round 12
// baseline (156.959 us; speedup 1.0000x reference)
//
#include <hip/hip_runtime.h>
#include <stdint.h>

// ---------- types & helpers ----------
typedef __attribute__((ext_vector_type(4))) float    f32x4;
typedef f32x4 __attribute__((aligned(4)))   f32x4u;  // 4B-aligned vector load (global allows it)
typedef __attribute__((ext_vector_type(8))) short    bf16x8;   // 8 bf16 (4 VGPRs) — MFMA operand
typedef __attribute__((ext_vector_type(2))) uint32_t u32x2;
typedef __attribute__((ext_vector_type(4))) uint32_t u32x4;

#define MFMA16(a,b,c) __builtin_amdgcn_mfma_f32_16x16x32_bf16((a),(b),(c),0,0,0)

__device__ __forceinline__ uint16_t f2bf(float f){
  uint32_t u = __float_as_uint(f);
  return (uint16_t)((u + 0x7FFFu + ((u >> 16) & 1u)) >> 16);   // RNE
}

// packed f32x2 -> bf16x2 (RNE), single instruction
__device__ __forceinline__ uint32_t pk_bf16(float lo, float hi){
  uint32_t r; asm("v_cvt_pk_bf16_f32 %0, %1, %2" : "=v"(r) : "v"(lo), "v"(hi)); return r;
}

__device__ __forceinline__ float fast_exp2(float x){
  float r; asm("v_exp_f32 %0, %1" : "=v"(r) : "v"(x)); return r;
}
__device__ __forceinline__ float fast_log2(float x){
  float r; asm("v_log_f32 %0, %1" : "=v"(r) : "v"(x)); return r;
}

__device__ __forceinline__ float bfl(uint32_t u){ return __uint_as_float(u << 16); }
__device__ __forceinline__ float bfh(uint32_t u){ return __uint_as_float(u & 0xffff0000u); }

// async global->LDS, 16B per lane; LDS dest must be (wave-uniform base + lane*16)
__device__ __forceinline__ void gload16(const uint16_t* g, uint16_t* l){
  __builtin_amdgcn_global_load_lds((const __attribute__((address_space(1))) uint32_t*)g,
                                   (__attribute__((address_space(3))) uint32_t*)l, 16, 0, 0);
}

// ---------- prep: x->bf16 (blocks 0..4095) + bias transpose (blocks 4096..4351) ----------
__global__ void k_cvtb(const float* __restrict__ in, uint16_t* __restrict__ out,
                       const float* __restrict__ btab, float* __restrict__ bias_t){
  const int bx = blockIdx.x;
  if (bx < 4096){
    const size_t i = (size_t)(bx*256 + threadIdx.x) * 4;
    const f32x4 v = *(const f32x4*)(in + i);
    u32x2 pk = {pk_bf16(v[0], v[1]), pk_bf16(v[2], v[3])};
    *(u32x2*)(out + i) = pk;
  } else {
    const int i = (bx - 4096)*256 + threadIdx.x;
    if (i < 4095*16) bias_t[(i & 15)*4096 + (i >> 4)] = btab[i] * 1.4426950408889634f;
  }
}

__global__ void k_tcvt(const float* __restrict__ in, uint16_t* __restrict__ out, int K, int N){
  __shared__ float tile[64][65];
  const int k0 = blockIdx.y*64, n0 = blockIdx.x*64;
  const int tc = threadIdx.x & 63, tr = threadIdx.x >> 6;
  #pragma unroll
  for (int p=0;p<16;p++){ int r = p*4 + tr; tile[r][tc] = in[(size_t)(k0+r)*N + n0 + tc]; }
  __syncthreads();
  #pragma unroll
  for (int p=0;p<16;p++){ int r = p*4 + tr; out[(size_t)(n0+r)*K + k0 + tc] = f2bf(tile[tc][r]); }
}

// ---------- GEMM0: C(4096 x 3072) = A * Bt^T, BM=BN=128, BK=64; q/k/v scatter ----------
__global__ __launch_bounds__(256, 2) void k_gemm(
    const uint16_t* __restrict__ A, const uint16_t* __restrict__ Bt,
    const float* __restrict__ bias,
    uint16_t* __restrict__ qo, uint16_t* __restrict__ ko, uint16_t* __restrict__ vto)
{
  __shared__ __align__(16) uint16_t at[128*64];   // [row 128B = 8 chunks], chunk ^= row&7
  __shared__ __align__(16) uint16_t bt[128*64];
  const int tid = threadIdx.x;
  const int lane = tid & 63, w = tid >> 6;
  const int g = lane >> 4, li = lane & 15;
  const int wr = w >> 1, wc = w & 1;
  const int m0 = blockIdx.y * 128, n0 = blockIdx.x * 128;

  f32x4 acc[4][4] = {};

  const int srow = tid >> 3;
  const int scg  = (tid & 7) ^ (srow & 7);

  for (int kt_ = 0; kt_ < 16; kt_++){
    const int kk = kt_*64;
    __syncthreads();
    #pragma unroll
    for (int j = 0; j < 4; j++){
      gload16(A  + (size_t)(m0 + j*32 + srow)*1024 + kk + scg*8, at + (j*256+tid)*8);
      gload16(Bt + (size_t)(n0 + j*32 + srow)*1024 + kk + scg*8, bt + (j*256+tid)*8);
    }
    asm volatile("s_waitcnt vmcnt(0)" ::: "memory");
    __syncthreads();

    bf16x8 af[2][4], bfr[2][4];
    #pragma unroll
    for (int mi=0; mi<4; mi++){
      int row = wr*64 + mi*16 + li, sw = row & 7;
      af[0][mi] = *(const bf16x8*)(at + row*64 + ((g     ^ sw)*8));
      af[1][mi] = *(const bf16x8*)(at + row*64 + (((4+g) ^ sw)*8));
    }
    #pragma unroll
    for (int ni=0; ni<4; ni++){
      int row = wc*64 + ni*16 + li, sw = row & 7;
      bfr[0][ni] = *(const bf16x8*)(bt + row*64 + ((g     ^ sw)*8));
      bfr[1][ni] = *(const bf16x8*)(bt + row*64 + (((4+g) ^ sw)*8));
    }
    #pragma unroll
    for (int s=0; s<2; s++)
      #pragma unroll
      for (int mi=0; mi<4; mi++)
        #pragma unroll
        for (int ni=0; ni<4; ni++)
          acc[mi][ni] = MFMA16(af[s][mi], bfr[s][ni], acc[mi][ni]);
  }

  #pragma unroll
  for (int ni=0; ni<4; ni++){
    const int c = n0 + wc*64 + ni*16 + li;
    const float bv = bias[c];
    const int which = c >> 10, cc = c & 1023;
    const int h = cc >> 6, d = cc & 63;
    #pragma unroll
    for (int mi=0; mi<4; mi++){
      const int trow = m0 + wr*64 + mi*16 + g*4;
      const int b_ = trow >> 11, lcl = trow & 2047;
      const f32x4 v4 = acc[mi][ni];
      if (which == 0){
        uint16_t* dst = qo + (((size_t)(b_*16 + h)*2048 + lcl)*64 + d);
        #pragma unroll
        for (int r=0;r<4;r++) dst[(size_t)r*64] = f2bf((v4[r] + bv) * 0.18033688011112042f);
      } else if (which == 1){
        uint16_t* dst = ko + (((size_t)(b_*16 + h)*2048 + lcl)*64 + d);
        #pragma unroll
        for (int r=0;r<4;r++) dst[(size_t)r*64] = f2bf(v4[r] + bv);
      } else {
        u32x2 pk = {pk_bf16(v4[0]+bv, v4[1]+bv), pk_bf16(v4[2]+bv, v4[3]+bv)};
        *(u32x2*)(vto + (((size_t)(b_*16 + h)*64 + d)*2048 + lcl)) = pk;
      }
    }
  }
}

// ---------- GEMM1 (proj) with FUSED LSE MERGE: C(4096 x 1024) = blend(o0,o1) * Bt^T ----------
// A-tile is reg-staged: each 16B chunk lies within one (token, head); per K-step the
// head is exactly kt_, so blend weights are 2 scalar s-loads + 2 exp2 + 1 rcp. Blended
// bf16 chunk is ds_write'n to the SAME LDS address gload16 used (identical swizzle).
// Removes k_merge (16.8MB rd + 8.4MB wr) and the ao_buf round-trip (8.4+8.4MB).
__global__ __launch_bounds__(256, 2) void k_gemm2(
    const uint16_t* __restrict__ op, const float* __restrict__ sp,
    const uint16_t* __restrict__ Bt,
    const float* __restrict__ bias, float* __restrict__ outf)
{
  __shared__ __align__(16) uint16_t at[128*64];   // 16KB
  __shared__ __align__(16) uint16_t bt[64*64];    // 8KB
  const int tid = threadIdx.x;
  const int lane = tid & 63, w = tid >> 6;
  const int g = lane >> 4, li = lane & 15;
  const int wr = w >> 1, wc = w & 1;
  const int m0 = blockIdx.y * 128, n0 = blockIdx.x * 64;

  f32x4 acc[4][2] = {};
  const int srow = tid >> 3;
  const int scg  = (tid & 7) ^ (srow & 7);

  for (int kt_ = 0; kt_ < 16; kt_++){
    const int kk = kt_*64;
    __syncthreads();                               // prev-iter LDS reads done
    // B: async global->LDS
    #pragma unroll
    for (int j = 0; j < 2; j++)
      gload16(Bt + (size_t)(n0 + j*32 + srow)*1024 + kk + scg*8, bt + (j*256+tid)*8);
    // A: reg-staged LSE blend of the two KV-split halves
    #pragma unroll
    for (int j = 0; j < 4; j++){
      const int token = m0 + j*32 + srow;
      const float s0 = sp[token*16 + kt_];
      const float s1 = sp[65536 + token*16 + kt_];
      const float sm = fmaxf(s0, s1);
      float w0 = fast_exp2(s0 - sm), w1 = fast_exp2(s1 - sm);
      const float winv = 1.0f / (w0 + w1);
      w0 *= winv; w1 *= winv;
      const uint16_t* ap = op + (size_t)token*1024 + kk + scg*8;
      const u32x4 a = *(const u32x4*)(ap);
      const u32x4 b = *(const u32x4*)(ap + 4194304);   // other split half
      u32x4 r;
      #pragma unroll
      for (int e=0;e<4;e++){
        const float e0 = w0*bfl(a[e]) + w1*bfl(b[e]);
        const float e1 = w0*bfh(a[e]) + w1*bfh(b[e]);
        r[e] = pk_bf16(e0, e1);
      }
      *(u32x4*)(at + (j*256+tid)*8) = r;
    }
    asm volatile("s_waitcnt vmcnt(0)" ::: "memory");   // B gloads drained (A already consumed)
    __syncthreads();

    bf16x8 af[2][4], bfr[2][2];
    #pragma unroll
    for (int mi=0; mi<4; mi++){
      int row = wr*64 + mi*16 + li, sw = row & 7;
      af[0][mi] = *(const bf16x8*)(at + row*64 + ((g     ^ sw)*8));
      af[1][mi] = *(const bf16x8*)(at + row*64 + (((4+g) ^ sw)*8));
    }
    #pragma unroll
    for (int ni=0; ni<2; ni++){
      int row = wc*32 + ni*16 + li, sw = row & 7;
      bfr[0][ni] = *(const bf16x8*)(bt + row*64 + ((g     ^ sw)*8));
      bfr[1][ni] = *(const bf16x8*)(bt + row*64 + (((4+g) ^ sw)*8));
    }
    #pragma unroll
    for (int s=0; s<2; s++)
      #pragma unroll
      for (int mi=0; mi<4; mi++)
        #pragma unroll
        for (int ni=0; ni<2; ni++)
          acc[mi][ni] = MFMA16(af[s][mi], bfr[s][ni], acc[mi][ni]);
  }

  #pragma unroll
  for (int ni=0; ni<2; ni++){
    const int c = n0 + wc*32 + ni*16 + li;
    const float bv = bias[c];
    #pragma unroll
    for (int mi=0; mi<4; mi++){
      const int trow = m0 + wr*64 + mi*16 + g*4;
      float* dst = outf + (size_t)trow*1024 + c;
      const f32x4 v4 = acc[mi][ni];
      #pragma unroll
      for (int r=0;r<4;r++) dst[(size_t)r*1024] = v4[r] + bv;
    }
  }
}

// ---------- flash attention: 4 waves x 32 q, KVBLK=64, KV-SPLIT=2 (unchanged from r11) ----------
// NOTE: launch_bounds stays (256,2) — (256,4) spills catastrophically (r8).
__device__ __forceinline__ void attn_tile(
    int t, bool last, int tid, int g, int li, int srow, int scg,
    const uint16_t* kbase, const uint16_t* vbase, const float* bb,
    const uint16_t* ktc, uint16_t* ktn, const uint16_t* vtc, uint16_t* vtn, uint16_t* pl,
    const bf16x8 (&qf)[2][2], bf16x8 ones,
    f32x4 (&o)[4][2], f32x4 (&o4)[2], float& mrun0, float& mrun1)
{
  const int kv0 = t*64;

  // bias for THIS tile: 5 diagonal windows; bv[c=0][mf]=bv5[mf+1], bv[c=1][mf]=bv5[mf]
  f32x4 bv5[5];
  #pragma unroll
  for (int j=0;j<5;j++)
    bv5[j] = *(const f32x4u*)(bb + kv0 + (j-1)*16 + g*4 - li);
  asm volatile("" ::: "memory");                           // pin issue order: bias -> staging

  if (!last){
    const int kv1 = kv0 + 64;
    gload16(kbase + (size_t)(kv1+srow)*64 + scg*8,         ktn + tid*8);
    gload16(kbase + (size_t)(kv1+srow+32)*64 + scg*8,      ktn + 2048 + tid*8);
    gload16(vbase + (size_t)srow*2048 + kv1 + scg*8,       vtn + tid*8);
    gload16(vbase + (size_t)(srow+32)*2048 + kv1 + scg*8,  vtn + 2048 + tid*8);
    // queue (old->new): stage(t)4, bias(t)5, stage(t+1)4 = 13 outstanding
    asm volatile("s_waitcnt vmcnt(9)" ::: "memory");       // retire stage(t); keep bias+stage(t+1)
  } else {
    asm volatile("s_waitcnt vmcnt(5)" ::: "memory");       // retire stage(t); keep bias(t)
  }
  __builtin_amdgcn_s_barrier();                            // A: tile t ready

  // S^T(64kv x 32q) = K * Q^T   (K-frags shared across both q col-blocks)
  f32x4 sa[4][2];
  __builtin_amdgcn_s_setprio(1);
  #pragma unroll
  for (int mf=0; mf<4; mf++){
    const int row = mf*16 + li, sw = row & 7;
    bf16x8 a0 = *(const bf16x8*)(ktc + row*64 + ((g     ^ sw)*8));
    bf16x8 a1 = *(const bf16x8*)(ktc + row*64 + (((4+g) ^ sw)*8));
    #pragma unroll
    for (int c=0;c<2;c++){
      f32x4 cfr = {};
      cfr = MFMA16(a0, qf[c][0], cfr);
      cfr = MFMA16(a1, qf[c][1], cfr);
      sa[mf][c] = cfr;
    }
  }
  __builtin_amdgcn_s_setprio(0);

  // bias add + lane-local max (q = c*16+li; kv = mf*16+g*4+r)
  float t0 = -__builtin_inff(), t1 = -__builtin_inff();
  #pragma unroll
  for (int mf=0; mf<4; mf++){
    sa[mf][0] += bv5[mf+1];
    sa[mf][1] += bv5[mf];
    #pragma unroll
    for (int r=0; r<4; r++){
      t0 = fmaxf(t0, sa[mf][0][r]);
      t1 = fmaxf(t1, sa[mf][1][r]);
    }
  }

  // defer-max (T13): common path has NO cross-lane ops; rare path full reduce.
  const int ok = (t0 <= mrun0 + 8.f) && (t1 <= mrun1 + 8.f);
  if (!__all(ok)){
    float r0 = t0, r1 = t1;
    r0 = fmaxf(r0, __shfl_xor(r0, 16)); r0 = fmaxf(r0, __shfl_xor(r0, 32));
    r1 = fmaxf(r1, __shfl_xor(r1, 16)); r1 = fmaxf(r1, __shfl_xor(r1, 32));
    const float mn0 = fmaxf(mrun0, r0), mn1 = fmaxf(mrun1, r1);
    const float a0 = fast_exp2(mrun0 - mn0), a1 = fast_exp2(mrun1 - mn1);
    #pragma unroll
    for (int mf=0; mf<4; mf++){ o[mf][0] *= a0; o[mf][1] *= a1; }
    o4[0] *= a0; o4[1] *= a1;
    mrun0 = mn0; mrun1 = mn1;
  }

  // V fragments (shared by both c-blocks)
  bf16x8 av[2][4];
  #pragma unroll
  for (int s=0; s<2; s++)
    #pragma unroll
    for (int mf=0; mf<4; mf++){
      const int row = mf*16 + li, sw = row & 7;
      av[s][mf] = *(const bf16x8*)(vtc + row*64 + (((4*s+g) ^ sw)*8));
    }

  // per c-block: P = exp2(S-m) -> bf16 -> P-slab (REUSED across c: 2KB/wave) -> PV
  const int swp2 = 2*(li & 7);
  #pragma unroll
  for (int c=0;c<2;c++){
    const float mr = c ? mrun1 : mrun0;
    #pragma unroll
    for (int mf=0; mf<4; mf++){
      float p0 = fast_exp2(sa[mf][c][0] - mr);
      float p1 = fast_exp2(sa[mf][c][1] - mr);
      float p2 = fast_exp2(sa[mf][c][2] - mr);
      float p3 = fast_exp2(sa[mf][c][3] - mr);
      u32x2 pk = {pk_bf16(p0,p1), pk_bf16(p2,p3)};
      *(u32x2*)(pl + li*64 + (((4*mf+g) ^ swp2)*4)) = pk;
    }
    __builtin_amdgcn_s_setprio(1);
    #pragma unroll
    for (int s=0; s<2; s++){
      bf16x8 pb = *(const bf16x8*)(pl + li*64 + (((8*s+2*g) ^ swp2)*4));
      o4[c] = MFMA16(ones, pb, o4[c]);
      #pragma unroll
      for (int mf=0; mf<4; mf++)
        o[mf][c] = MFMA16(av[s][mf], pb, o[mf][c]);
    }
    __builtin_amdgcn_s_setprio(0);
  }
  __builtin_amdgcn_s_barrier();                            // B: done reading tile t
}

__global__ __launch_bounds__(256, 2) void k_attn(
    const uint16_t* __restrict__ qg, const uint16_t* __restrict__ kg,
    const uint16_t* __restrict__ vg, const float* __restrict__ biast,
    uint16_t* __restrict__ opart, float* __restrict__ spart)
{
  __shared__ __align__(16) uint16_t kt[2][64*64];  // K tile [kv][d], 16B-chunk ^= row&7 (16KB)
  __shared__ __align__(16) uint16_t vt[2][64*64];  // V^T tile [d][kv], same swizzle   (16KB)
  __shared__ __align__(16) uint16_t pt[4][16*64];  // per-wave P^T [16q][64kv], reused  (8KB)
  const int tid = threadIdx.x;
  const int lane = tid & 63, w = tid >> 6;         // 4 waves
  const int g = lane >> 4, li = lane & 15;
  const int bh = blockIdx.y, h = bh & 15, b_ = bh >> 4;
  const int id = blockIdx.x;                       // 32 = 16 q-chunks x 2 kv-splits
  const int split = id & 1, qxi = id >> 1;
  const int qw = qxi*128 + w*32;                   // wave's q base (32 rows)
  const int tg0 = split*16;                        // this block's 16 kv tiles

  bf16x8 qf[2][2];
  #pragma unroll
  for (int c=0;c<2;c++){
    const uint16_t* qp = qg + ((size_t)bh*2048 + qw + c*16 + li)*64 + g*8;
    qf[c][0] = *(const bf16x8*)(qp);
    qf[c][1] = *(const bf16x8*)(qp + 32);
  }
  bf16x8 ones = (bf16x8)(short)0;                  // A-frag: row 0 = 1.0, rows 1-15 = 0
  if (li == 0){ const short v = (short)0x3F80; ones = (bf16x8){v,v,v,v,v,v,v,v}; }

  f32x4 o[4][2] = {};
  f32x4 o4[2] = {};
  float mrun0 = -__builtin_inff(), mrun1 = -__builtin_inff();

  const uint16_t* kbase = kg + (size_t)bh*(2048*64);
  const uint16_t* vbase = vg + (size_t)bh*(64*2048);
  const int srow = tid >> 3;                       // 0..31
  const int scg  = (tid & 7) ^ (srow & 7);
  const float* bb = biast + h*4096 + 2047 - qw;    // + kv - (c*16+li)
  uint16_t* pl = &pt[w][0];

  // prologue: stage first tile of this split
  const int kvp = tg0*64;
  gload16(kbase + (size_t)(kvp+srow)*64 + scg*8,        &kt[0][tid*8]);
  gload16(kbase + (size_t)(kvp+srow+32)*64 + scg*8,     &kt[0][2048 + tid*8]);
  gload16(vbase + (size_t)srow*2048 + kvp + scg*8,      &vt[0][tid*8]);
  gload16(vbase + (size_t)(srow+32)*2048 + kvp + scg*8, &vt[0][2048 + tid*8]);

  for (int tt = 0; tt < 16; tt += 2){
    attn_tile(tg0+tt,   false,      tid, g, li, srow, scg, kbase, vbase, bb,
              &kt[0][0], &kt[1][0], &vt[0][0], &vt[1][0], pl,
              qf, ones, o, o4, mrun0, mrun1);
    attn_tile(tg0+tt+1, tt == 14,   tid, g, li, srow, scg, kbase, vbase, bb,
              &kt[1][0], &kt[0][0], &vt[1][0], &vt[0][0], pl,
              qf, ones, o, o4, mrun0, mrun1);
  }

  // row sums in o4[c] reg 0 of g=0 lanes; broadcast; emit normalized O + s = m + log2(l)
  const float ls0 = __shfl(o4[0][0], li);
  const float ls1 = __shfl(o4[1][0], li);
  const float inv0 = 1.0f / ls0, inv1 = 1.0f / ls1;
  const float sv0 = mrun0 + fast_log2(ls0);
  const float sv1 = mrun1 + fast_log2(ls1);
  #pragma unroll
  for (int c=0;c<2;c++){
    const float inv = c ? inv1 : inv0;
    const int token = b_*2048 + qw + c*16 + li;     // 0..4095
    if (g == 0) spart[split*65536 + token*16 + h] = c ? sv1 : sv0;
    uint16_t* dst = opart + ((size_t)(split*4096 + token))*1024 + h*64;
    #pragma unroll
    for (int mf=0; mf<4; mf++){
      u32x2 pk = {pk_bf16(o[mf][c][0]*inv, o[mf][c][1]*inv),
                  pk_bf16(o[mf][c][2]*inv, o[mf][c][3]*inv)};
      *(u32x2*)(dst + mf*16 + g*4) = pk;
    }
  }
}

// ---------- launch ----------
extern "C" void kernel_launch(void* const* d_in, const int* in_sizes, int n_in,
                              void* d_out, int out_size, void* d_ws, size_t ws_size,
                              hipStream_t stream)
{
  const float* x      = (const float*)d_in[0];
  const float* qkv_w  = (const float*)d_in[1];
  const float* qkv_b  = (const float*)d_in[2];
  const float* proj_w = (const float*)d_in[3];
  const float* proj_b = (const float*)d_in[4];
  const float* btab   = (const float*)d_in[5];
  float* out = (float*)d_out;

  // workspace layout (lifetimes disjoint where overlapped):
  //   [0 .. 8.4MB)      x_bf   (dead after gemm0)   } o_part (16.8MB) overlays both,
  //   [8.4 .. 14.7MB)   qkv_wt (dead after gemm0)   } written by attn, read by gemm2
  //   [16.8 .. 25.2MB)  q_buf
  //   [25.2 .. 33.6MB)  k_buf
  //   [33.6 .. 41.9MB)  vt_buf
  //   [41.9 .. 44.0MB)  proj_wt (live till gemm2; moved out of o_part's way)
  //   [44.0 .. 44.6MB)  s_part  (2 x 4096 x 16 f32)
  //   [50.33.. 50.59MB) bias_t
  char* p = (char*)d_ws;
  uint16_t* x_bf    = (uint16_t*)(p);
  uint16_t* qkv_wt  = (uint16_t*)(p + 8388608);
  uint16_t* q_buf   = (uint16_t*)(p + 16777216);   // (b,h,l,d) bf16, prescaled
  uint16_t* k_buf   = (uint16_t*)(p + 25165824);   // (b,h,l,d) bf16
  uint16_t* vt_buf  = (uint16_t*)(p + 33554432);   // (b,h,d,l) bf16
  uint16_t* proj_wt = (uint16_t*)(p + 41943040);
  float*    s_part  = (float*)   (p + 44040192);
  float*    bias_t  = (float*)   (p + 50331648);   // 16 x 4096 f32, *log2e
  uint16_t* o_part  = (uint16_t*)(p);              // 2 x 4096 x 1024 bf16, over x_bf+qkv_wt

  k_cvtb <<<dim3(4352),  dim3(256), 0, stream>>>(x, x_bf, btab, bias_t);
  k_tcvt <<<dim3(48,16), dim3(256), 0, stream>>>(qkv_w,  qkv_wt,  1024, 3072);
  k_tcvt <<<dim3(16,16), dim3(256), 0, stream>>>(proj_w, proj_wt, 1024, 1024);

  k_gemm   <<<dim3(24,32), dim3(256), 0, stream>>>(x_bf, qkv_wt, qkv_b, q_buf, k_buf, vt_buf);
  k_attn   <<<dim3(32,32), dim3(256), 0, stream>>>(q_buf, k_buf, vt_buf, bias_t, o_part, s_part);
  k_gemm2  <<<dim3(16,32), dim3(256), 0, stream>>>(o_part, s_part, proj_wt, proj_b, out);
}

// Round 13
// 132.759 us; speedup vs baseline: 1.1823x; 1.1823x over previous
//
#include <hip/hip_runtime.h>
#include <stdint.h>

// ---------- types & helpers ----------
typedef __attribute__((ext_vector_type(4))) float    f32x4;
typedef f32x4 __attribute__((aligned(4)))   f32x4u;  // 4B-aligned vector load (global allows it)
typedef __attribute__((ext_vector_type(8))) short    bf16x8;   // 8 bf16 (4 VGPRs) — MFMA operand
typedef __attribute__((ext_vector_type(2))) uint32_t u32x2;
typedef __attribute__((ext_vector_type(4))) uint32_t u32x4;

#define MFMA16(a,b,c) __builtin_amdgcn_mfma_f32_16x16x32_bf16((a),(b),(c),0,0,0)

__device__ __forceinline__ uint16_t f2bf(float f){
  uint32_t u = __float_as_uint(f);
  return (uint16_t)((u + 0x7FFFu + ((u >> 16) & 1u)) >> 16);   // RNE
}

// packed f32x2 -> bf16x2 (RNE), single instruction
__device__ __forceinline__ uint32_t pk_bf16(float lo, float hi){
  uint32_t r; asm("v_cvt_pk_bf16_f32 %0, %1, %2" : "=v"(r) : "v"(lo), "v"(hi)); return r;
}

__device__ __forceinline__ float fast_exp2(float x){
  float r; asm("v_exp_f32 %0, %1" : "=v"(r) : "v"(x)); return r;
}
__device__ __forceinline__ float fast_log2(float x){
  float r; asm("v_log_f32 %0, %1" : "=v"(r) : "v"(x)); return r;
}

__device__ __forceinline__ float bfl(uint32_t u){ return __uint_as_float(u << 16); }
__device__ __forceinline__ float bfh(uint32_t u){ return __uint_as_float(u & 0xffff0000u); }

// async global->LDS, 16B per lane; LDS dest must be (wave-uniform base + lane*16)
__device__ __forceinline__ void gload16(const uint16_t* g, uint16_t* l){
  __builtin_amdgcn_global_load_lds((const __attribute__((address_space(1))) uint32_t*)g,
                                   (__attribute__((address_space(3))) uint32_t*)l, 16, 0, 0);
}

// ---------- prep: x->bf16 (blocks 0..4095) + bias transpose (blocks 4096..4351) ----------
__global__ void k_cvtb(const float* __restrict__ in, uint16_t* __restrict__ out,
                       const float* __restrict__ btab, float* __restrict__ bias_t){
  const int bx = blockIdx.x;
  if (bx < 4096){
    const size_t i = (size_t)(bx*256 + threadIdx.x) * 4;
    const f32x4 v = *(const f32x4*)(in + i);
    u32x2 pk = {pk_bf16(v[0], v[1]), pk_bf16(v[2], v[3])};
    *(u32x2*)(out + i) = pk;
  } else {
    const int i = (bx - 4096)*256 + threadIdx.x;
    if (i < 4095*16) bias_t[(i & 15)*4096 + (i >> 4)] = btab[i] * 1.4426950408889634f;
  }
}

__global__ void k_tcvt(const float* __restrict__ in, uint16_t* __restrict__ out, int K, int N){
  __shared__ float tile[64][65];
  const int k0 = blockIdx.y*64, n0 = blockIdx.x*64;
  const int tc = threadIdx.x & 63, tr = threadIdx.x >> 6;
  #pragma unroll
  for (int p=0;p<16;p++){ int r = p*4 + tr; tile[r][tc] = in[(size_t)(k0+r)*N + n0 + tc]; }
  __syncthreads();
  #pragma unroll
  for (int p=0;p<16;p++){ int r = p*4 + tr; out[(size_t)(n0+r)*K + k0 + tc] = f2bf(tile[tc][r]); }
}

// ---------- GEMM0: C(4096 x 3072) = A * Bt^T, BM=BN=128, BK=64; q/k/v scatter ----------
// 2-phase counted-vmcnt double-buffer (T3-minimal+T4, proven on attn r2->r3): prefetch
// K-tile t+1 while computing t; vmcnt(8) retires exactly stage(t) (queue old->new:
// stage(t) 8, stage(t+1) 8). Removes the per-step vmcnt(0) HBM-latency drain.
__global__ __launch_bounds__(256, 2) void k_gemm(
    const uint16_t* __restrict__ A, const uint16_t* __restrict__ Bt,
    const float* __restrict__ bias,
    uint16_t* __restrict__ qo, uint16_t* __restrict__ ko, uint16_t* __restrict__ vto)
{
  __shared__ __align__(16) uint16_t at[2][128*64];   // 2 x 16KB, chunk ^= row&7
  __shared__ __align__(16) uint16_t bt[2][128*64];   // 2 x 16KB
  const int tid = threadIdx.x;
  const int lane = tid & 63, w = tid >> 6;
  const int g = lane >> 4, li = lane & 15;
  const int wr = w >> 1, wc = w & 1;
  const int m0 = blockIdx.y * 128, n0 = blockIdx.x * 128;

  f32x4 acc[4][4] = {};

  const int srow = tid >> 3;
  const int scg  = (tid & 7) ^ (srow & 7);

  // prologue: stage K-tile 0 into buffer 0
  #pragma unroll
  for (int j = 0; j < 4; j++){
    gload16(A  + (size_t)(m0 + j*32 + srow)*1024 + scg*8, &at[0][(j*256+tid)*8]);
    gload16(Bt + (size_t)(n0 + j*32 + srow)*1024 + scg*8, &bt[0][(j*256+tid)*8]);
  }

  for (int kt_ = 0; kt_ < 16; kt_++){
    const int cur = kt_ & 1;
    if (kt_ < 15){
      const int kk1 = (kt_+1)*64;
      #pragma unroll
      for (int j = 0; j < 4; j++){
        gload16(A  + (size_t)(m0 + j*32 + srow)*1024 + kk1 + scg*8, &at[cur^1][(j*256+tid)*8]);
        gload16(Bt + (size_t)(n0 + j*32 + srow)*1024 + kk1 + scg*8, &bt[cur^1][(j*256+tid)*8]);
      }
      asm volatile("s_waitcnt vmcnt(8)" ::: "memory");   // stage(t) done; t+1 in flight
    } else {
      asm volatile("s_waitcnt vmcnt(0)" ::: "memory");
    }
    __builtin_amdgcn_s_barrier();                        // A: tile t ready
    const uint16_t* atc = &at[cur][0];
    const uint16_t* btc = &bt[cur][0];

    bf16x8 af[2][4], bfr[2][4];
    #pragma unroll
    for (int mi=0; mi<4; mi++){
      int row = wr*64 + mi*16 + li, sw = row & 7;
      af[0][mi] = *(const bf16x8*)(atc + row*64 + ((g     ^ sw)*8));
      af[1][mi] = *(const bf16x8*)(atc + row*64 + (((4+g) ^ sw)*8));
    }
    #pragma unroll
    for (int ni=0; ni<4; ni++){
      int row = wc*64 + ni*16 + li, sw = row & 7;
      bfr[0][ni] = *(const bf16x8*)(btc + row*64 + ((g     ^ sw)*8));
      bfr[1][ni] = *(const bf16x8*)(btc + row*64 + (((4+g) ^ sw)*8));
    }
    #pragma unroll
    for (int s=0; s<2; s++)
      #pragma unroll
      for (int mi=0; mi<4; mi++)
        #pragma unroll
        for (int ni=0; ni<4; ni++)
          acc[mi][ni] = MFMA16(af[s][mi], bfr[s][ni], acc[mi][ni]);
    __builtin_amdgcn_s_barrier();                        // B: done reading buf[cur]
  }

  #pragma unroll
  for (int ni=0; ni<4; ni++){
    const int c = n0 + wc*64 + ni*16 + li;
    const float bv = bias[c];
    const int which = c >> 10, cc = c & 1023;
    const int h = cc >> 6, d = cc & 63;
    #pragma unroll
    for (int mi=0; mi<4; mi++){
      const int trow = m0 + wr*64 + mi*16 + g*4;
      const int b_ = trow >> 11, lcl = trow & 2047;
      const f32x4 v4 = acc[mi][ni];
      if (which == 0){
        uint16_t* dst = qo + (((size_t)(b_*16 + h)*2048 + lcl)*64 + d);
        #pragma unroll
        for (int r=0;r<4;r++) dst[(size_t)r*64] = f2bf((v4[r] + bv) * 0.18033688011112042f);
      } else if (which == 1){
        uint16_t* dst = ko + (((size_t)(b_*16 + h)*2048 + lcl)*64 + d);
        #pragma unroll
        for (int r=0;r<4;r++) dst[(size_t)r*64] = f2bf(v4[r] + bv);
      } else {
        u32x2 pk = {pk_bf16(v4[0]+bv, v4[1]+bv), pk_bf16(v4[2]+bv, v4[3]+bv)};
        *(u32x2*)(vto + (((size_t)(b_*16 + h)*64 + d)*2048 + lcl)) = pk;
      }
    }
  }
}

// ---------- GEMM1 (proj): C(4096 x 1024) = A * Bt^T, BM=128, BN=64 -> 512 blocks ----------
__global__ __launch_bounds__(256, 2) void k_gemm2(
    const uint16_t* __restrict__ A, const uint16_t* __restrict__ Bt,
    const float* __restrict__ bias, float* __restrict__ outf)
{
  __shared__ __align__(16) uint16_t at[128*64];   // 16KB
  __shared__ __align__(16) uint16_t bt[64*64];    // 8KB
  const int tid = threadIdx.x;
  const int lane = tid & 63, w = tid >> 6;
  const int g = lane >> 4, li = lane & 15;
  const int wr = w >> 1, wc = w & 1;
  const int m0 = blockIdx.y * 128, n0 = blockIdx.x * 64;

  f32x4 acc[4][2] = {};
  const int srow = tid >> 3;
  const int scg  = (tid & 7) ^ (srow & 7);

  for (int kt_ = 0; kt_ < 16; kt_++){
    const int kk = kt_*64;
    __syncthreads();
    #pragma unroll
    for (int j = 0; j < 4; j++)
      gload16(A  + (size_t)(m0 + j*32 + srow)*1024 + kk + scg*8, at + (j*256+tid)*8);
    #pragma unroll
    for (int j = 0; j < 2; j++)
      gload16(Bt + (size_t)(n0 + j*32 + srow)*1024 + kk + scg*8, bt + (j*256+tid)*8);
    asm volatile("s_waitcnt vmcnt(0)" ::: "memory");
    __syncthreads();

    bf16x8 af[2][4], bfr[2][2];
    #pragma unroll
    for (int mi=0; mi<4; mi++){
      int row = wr*64 + mi*16 + li, sw = row & 7;
      af[0][mi] = *(const bf16x8*)(at + row*64 + ((g     ^ sw)*8));
      af[1][mi] = *(const bf16x8*)(at + row*64 + (((4+g) ^ sw)*8));
    }
    #pragma unroll
    for (int ni=0; ni<2; ni++){
      int row = wc*32 + ni*16 + li, sw = row & 7;
      bfr[0][ni] = *(const bf16x8*)(bt + row*64 + ((g     ^ sw)*8));
      bfr[1][ni] = *(const bf16x8*)(bt + row*64 + (((4+g) ^ sw)*8));
    }
    #pragma unroll
    for (int s=0; s<2; s++)
      #pragma unroll
      for (int mi=0; mi<4; mi++)
        #pragma unroll
        for (int ni=0; ni<2; ni++)
          acc[mi][ni] = MFMA16(af[s][mi], bfr[s][ni], acc[mi][ni]);
  }

  #pragma unroll
  for (int ni=0; ni<2; ni++){
    const int c = n0 + wc*32 + ni*16 + li;
    const float bv = bias[c];
    #pragma unroll
    for (int mi=0; mi<4; mi++){
      const int trow = m0 + wr*64 + mi*16 + g*4;
      float* dst = outf + (size_t)trow*1024 + c;
      const f32x4 v4 = acc[mi][ni];
      #pragma unroll
      for (int r=0;r<4;r++) dst[(size_t)r*1024] = v4[r] + bv;
    }
  }
}

// ---------- flash attention: 4 waves x 32 q, KVBLK=64, KV-SPLIT=2 (byte-identical to r11) ----------
// NOTE: launch_bounds stays (256,2) — (256,4) spills catastrophically (r8).
__device__ __forceinline__ void attn_tile(
    int t, bool last, int tid, int g, int li, int srow, int scg,
    const uint16_t* kbase, const uint16_t* vbase, const float* bb,
    const uint16_t* ktc, uint16_t* ktn, const uint16_t* vtc, uint16_t* vtn, uint16_t* pl,
    const bf16x8 (&qf)[2][2], bf16x8 ones,
    f32x4 (&o)[4][2], f32x4 (&o4)[2], float& mrun0, float& mrun1)
{
  const int kv0 = t*64;

  // bias for THIS tile: 5 diagonal windows; bv[c=0][mf]=bv5[mf+1], bv[c=1][mf]=bv5[mf]
  f32x4 bv5[5];
  #pragma unroll
  for (int j=0;j<5;j++)
    bv5[j] = *(const f32x4u*)(bb + kv0 + (j-1)*16 + g*4 - li);
  asm volatile("" ::: "memory");                           // pin issue order: bias -> staging

  if (!last){
    const int kv1 = kv0 + 64;
    gload16(kbase + (size_t)(kv1+srow)*64 + scg*8,         ktn + tid*8);
    gload16(kbase + (size_t)(kv1+srow+32)*64 + scg*8,      ktn + 2048 + tid*8);
    gload16(vbase + (size_t)srow*2048 + kv1 + scg*8,       vtn + tid*8);
    gload16(vbase + (size_t)(srow+32)*2048 + kv1 + scg*8,  vtn + 2048 + tid*8);
    // queue (old->new): stage(t)4, bias(t)5, stage(t+1)4 = 13 outstanding
    asm volatile("s_waitcnt vmcnt(9)" ::: "memory");       // retire stage(t); keep bias+stage(t+1)
  } else {
    asm volatile("s_waitcnt vmcnt(5)" ::: "memory");       // retire stage(t); keep bias(t)
  }
  __builtin_amdgcn_s_barrier();                            // A: tile t ready

  // S^T(64kv x 32q) = K * Q^T   (K-frags shared across both q col-blocks)
  f32x4 sa[4][2];
  __builtin_amdgcn_s_setprio(1);
  #pragma unroll
  for (int mf=0; mf<4; mf++){
    const int row = mf*16 + li, sw = row & 7;
    bf16x8 a0 = *(const bf16x8*)(ktc + row*64 + ((g     ^ sw)*8));
    bf16x8 a1 = *(const bf16x8*)(ktc + row*64 + (((4+g) ^ sw)*8));
    #pragma unroll
    for (int c=0;c<2;c++){
      f32x4 cfr = {};
      cfr = MFMA16(a0, qf[c][0], cfr);
      cfr = MFMA16(a1, qf[c][1], cfr);
      sa[mf][c] = cfr;
    }
  }
  __builtin_amdgcn_s_setprio(0);

  // bias add + lane-local max (q = c*16+li; kv = mf*16+g*4+r)
  float t0 = -__builtin_inff(), t1 = -__builtin_inff();
  #pragma unroll
  for (int mf=0; mf<4; mf++){
    sa[mf][0] += bv5[mf+1];
    sa[mf][1] += bv5[mf];
    #pragma unroll
    for (int r=0; r<4; r++){
      t0 = fmaxf(t0, sa[mf][0][r]);
      t1 = fmaxf(t1, sa[mf][1][r]);
    }
  }

  // defer-max (T13): common path has NO cross-lane ops; rare path full reduce.
  const int ok = (t0 <= mrun0 + 8.f) && (t1 <= mrun1 + 8.f);
  if (!__all(ok)){
    float r0 = t0, r1 = t1;
    r0 = fmaxf(r0, __shfl_xor(r0, 16)); r0 = fmaxf(r0, __shfl_xor(r0, 32));
    r1 = fmaxf(r1, __shfl_xor(r1, 16)); r1 = fmaxf(r1, __shfl_xor(r1, 32));
    const float mn0 = fmaxf(mrun0, r0), mn1 = fmaxf(mrun1, r1);
    const float a0 = fast_exp2(mrun0 - mn0), a1 = fast_exp2(mrun1 - mn1);
    #pragma unroll
    for (int mf=0; mf<4; mf++){ o[mf][0] *= a0; o[mf][1] *= a1; }
    o4[0] *= a0; o4[1] *= a1;
    mrun0 = mn0; mrun1 = mn1;
  }

  // V fragments (shared by both c-blocks)
  bf16x8 av[2][4];
  #pragma unroll
  for (int s=0; s<2; s++)
    #pragma unroll
    for (int mf=0; mf<4; mf++){
      const int row = mf*16 + li, sw = row & 7;
      av[s][mf] = *(const bf16x8*)(vtc + row*64 + (((4*s+g) ^ sw)*8));
    }

  // per c-block: P = exp2(S-m) -> bf16 -> P-slab (REUSED across c: 2KB/wave) -> PV
  const int swp2 = 2*(li & 7);
  #pragma unroll
  for (int c=0;c<2;c++){
    const float mr = c ? mrun1 : mrun0;
    #pragma unroll
    for (int mf=0; mf<4; mf++){
      float p0 = fast_exp2(sa[mf][c][0] - mr);
      float p1 = fast_exp2(sa[mf][c][1] - mr);
      float p2 = fast_exp2(sa[mf][c][2] - mr);
      float p3 = fast_exp2(sa[mf][c][3] - mr);
      u32x2 pk = {pk_bf16(p0,p1), pk_bf16(p2,p3)};
      *(u32x2*)(pl + li*64 + (((4*mf+g) ^ swp2)*4)) = pk;
    }
    __builtin_amdgcn_s_setprio(1);
    #pragma unroll
    for (int s=0; s<2; s++){
      bf16x8 pb = *(const bf16x8*)(pl + li*64 + (((8*s+2*g) ^ swp2)*4));
      o4[c] = MFMA16(ones, pb, o4[c]);
      #pragma unroll
      for (int mf=0; mf<4; mf++)
        o[mf][c] = MFMA16(av[s][mf], pb, o[mf][c]);
    }
    __builtin_amdgcn_s_setprio(0);
  }
  __builtin_amdgcn_s_barrier();                            // B: done reading tile t
}

__global__ __launch_bounds__(256, 2) void k_attn(
    const uint16_t* __restrict__ qg, const uint16_t* __restrict__ kg,
    const uint16_t* __restrict__ vg, const float* __restrict__ biast,
    uint16_t* __restrict__ opart, float* __restrict__ spart)
{
  __shared__ __align__(16) uint16_t kt[2][64*64];  // K tile [kv][d], 16B-chunk ^= row&7 (16KB)
  __shared__ __align__(16) uint16_t vt[2][64*64];  // V^T tile [d][kv], same swizzle   (16KB)
  __shared__ __align__(16) uint16_t pt[4][16*64];  // per-wave P^T [16q][64kv], reused  (8KB)
  const int tid = threadIdx.x;
  const int lane = tid & 63, w = tid >> 6;         // 4 waves
  const int g = lane >> 4, li = lane & 15;
  const int bh = blockIdx.y, h = bh & 15, b_ = bh >> 4;
  const int id = blockIdx.x;                       // 32 = 16 q-chunks x 2 kv-splits
  const int split = id & 1, qxi = id >> 1;
  const int qw = qxi*128 + w*32;                   // wave's q base (32 rows)
  const int tg0 = split*16;                        // this block's 16 kv tiles

  bf16x8 qf[2][2];
  #pragma unroll
  for (int c=0;c<2;c++){
    const uint16_t* qp = qg + ((size_t)bh*2048 + qw + c*16 + li)*64 + g*8;
    qf[c][0] = *(const bf16x8*)(qp);
    qf[c][1] = *(const bf16x8*)(qp + 32);
  }
  bf16x8 ones = (bf16x8)(short)0;                  // A-frag: row 0 = 1.0, rows 1-15 = 0
  if (li == 0){ const short v = (short)0x3F80; ones = (bf16x8){v,v,v,v,v,v,v,v}; }

  f32x4 o[4][2] = {};
  f32x4 o4[2] = {};
  float mrun0 = -__builtin_inff(), mrun1 = -__builtin_inff();

  const uint16_t* kbase = kg + (size_t)bh*(2048*64);
  const uint16_t* vbase = vg + (size_t)bh*(64*2048);
  const int srow = tid >> 3;                       // 0..31
  const int scg  = (tid & 7) ^ (srow & 7);
  const float* bb = biast + h*4096 + 2047 - qw;    // + kv - (c*16+li)
  uint16_t* pl = &pt[w][0];

  // prologue: stage first tile of this split
  const int kvp = tg0*64;
  gload16(kbase + (size_t)(kvp+srow)*64 + scg*8,        &kt[0][tid*8]);
  gload16(kbase + (size_t)(kvp+srow+32)*64 + scg*8,     &kt[0][2048 + tid*8]);
  gload16(vbase + (size_t)srow*2048 + kvp + scg*8,      &vt[0][tid*8]);
  gload16(vbase + (size_t)(srow+32)*2048 + kvp + scg*8, &vt[0][2048 + tid*8]);

  for (int tt = 0; tt < 16; tt += 2){
    attn_tile(tg0+tt,   false,      tid, g, li, srow, scg, kbase, vbase, bb,
              &kt[0][0], &kt[1][0], &vt[0][0], &vt[1][0], pl,
              qf, ones, o, o4, mrun0, mrun1);
    attn_tile(tg0+tt+1, tt == 14,   tid, g, li, srow, scg, kbase, vbase, bb,
              &kt[1][0], &kt[0][0], &vt[1][0], &vt[0][0], pl,
              qf, ones, o, o4, mrun0, mrun1);
  }

  // row sums in o4[c] reg 0 of g=0 lanes; broadcast; emit normalized O + s = m + log2(l)
  const float ls0 = __shfl(o4[0][0], li);
  const float ls1 = __shfl(o4[1][0], li);
  const float inv0 = 1.0f / ls0, inv1 = 1.0f / ls1;
  const float sv0 = mrun0 + fast_log2(ls0);
  const float sv1 = mrun1 + fast_log2(ls1);
  #pragma unroll
  for (int c=0;c<2;c++){
    const float inv = c ? inv1 : inv0;
    const int token = b_*2048 + qw + c*16 + li;     // 0..4095
    if (g == 0) spart[split*65536 + token*16 + h] = c ? sv1 : sv0;
    uint16_t* dst = opart + ((size_t)(split*4096 + token))*1024 + h*64;
    #pragma unroll
    for (int mf=0; mf<4; mf++){
      u32x2 pk = {pk_bf16(o[mf][c][0]*inv, o[mf][c][1]*inv),
                  pk_bf16(o[mf][c][2]*inv, o[mf][c][3]*inv)};
      *(u32x2*)(dst + mf*16 + g*4) = pk;
    }
  }
}

// ---------- LSE merge of the two KV-splits ----------
__global__ void k_merge(const uint16_t* __restrict__ op, const float* __restrict__ sp,
                        uint16_t* __restrict__ ao){
  const int gid = blockIdx.x*256 + threadIdx.x;    // 524288 threads, 8 cols each
  const int token = gid >> 7, col0 = (gid & 127) * 8, h = col0 >> 6;
  const float s0 = sp[token*16 + h], s1 = sp[65536 + token*16 + h];
  const float sm = fmaxf(s0, s1);
  float w0 = fast_exp2(s0 - sm), w1 = fast_exp2(s1 - sm);
  const float inv = 1.0f / (w0 + w1);
  w0 *= inv; w1 *= inv;
  const size_t i0 = (size_t)token*1024 + col0;
  const u32x4 a = *(const u32x4*)(op + i0);
  const u32x4 b = *(const u32x4*)(op + (size_t)4096*1024 + i0);
  u32x4 r;
  #pragma unroll
  for (int j=0;j<4;j++){
    const float e0 = w0*bfl(a[j]) + w1*bfl(b[j]);
    const float e1 = w0*bfh(a[j]) + w1*bfh(b[j]);
    r[j] = pk_bf16(e0, e1);
  }
  *(u32x4*)(ao + i0) = r;
}

// ---------- launch ----------
extern "C" void kernel_launch(void* const* d_in, const int* in_sizes, int n_in,
                              void* d_out, int out_size, void* d_ws, size_t ws_size,
                              hipStream_t stream)
{
  const float* x      = (const float*)d_in[0];
  const float* qkv_w  = (const float*)d_in[1];
  const float* qkv_b  = (const float*)d_in[2];
  const float* proj_w = (const float*)d_in[3];
  const float* proj_b = (const float*)d_in[4];
  const float* btab   = (const float*)d_in[5];
  float* out = (float*)d_out;

  char* p = (char*)d_ws;
  uint16_t* x_bf    = (uint16_t*)(p);
  uint16_t* qkv_wt  = (uint16_t*)(p + 8388608);
  uint16_t* proj_wt = (uint16_t*)(p + 14680064);
  uint16_t* q_buf   = (uint16_t*)(p + 16777216);   // (b,h,l,d) bf16, prescaled
  uint16_t* k_buf   = (uint16_t*)(p + 25165824);   // (b,h,l,d) bf16
  uint16_t* vt_buf  = (uint16_t*)(p + 33554432);   // (b,h,d,l) bf16
  uint16_t* ao_buf  = (uint16_t*)(p + 41943040);   // attn out (tokens x 1024) bf16
  float*    bias_t  = (float*)   (p + 50331648);   // 16 x 4096 f32, *log2e

  // scratch overlays (sequenced on the single stream):
  // o_part: 2 x 4096 x 1024 bf16 = 16.78MB  -> d_out (fully rewritten by gemm2 afterwards)
  // s_part: 2 x 4096 x 16 f32   = 0.5MB     -> x_bf region (dead after gemm0)
  uint16_t* o_part = (uint16_t*)d_out;
  float*    s_part = (float*)p;

  k_cvtb <<<dim3(4352),  dim3(256), 0, stream>>>(x, x_bf, btab, bias_t);
  k_tcvt <<<dim3(48,16), dim3(256), 0, stream>>>(qkv_w,  qkv_wt,  1024, 3072);
  k_tcvt <<<dim3(16,16), dim3(256), 0, stream>>>(proj_w, proj_wt, 1024, 1024);

  k_gemm   <<<dim3(24,32), dim3(256), 0, stream>>>(x_bf, qkv_wt, qkv_b, q_buf, k_buf, vt_buf);
  k_attn   <<<dim3(32,32), dim3(256), 0, stream>>>(q_buf, k_buf, vt_buf, bias_t, o_part, s_part);
  k_merge  <<<dim3(2048),  dim3(256), 0, stream>>>(o_part, s_part, ao_buf);
  k_gemm2  <<<dim3(16,32), dim3(256), 0, stream>>>(ao_buf, proj_wt, proj_b, out);
}

// Round 14
// 119.472 us; speedup vs baseline: 1.3138x; 1.1112x over previous
//
#include <hip/hip_runtime.h>
#include <stdint.h>

// ---------- types & helpers ----------
typedef __attribute__((ext_vector_type(4))) float    f32x4;
typedef f32x4 __attribute__((aligned(4)))   f32x4u;  // 4B-aligned vector load (global allows it)
typedef __attribute__((ext_vector_type(8))) short    bf16x8;   // 8 bf16 (4 VGPRs) — MFMA operand
typedef __attribute__((ext_vector_type(2))) uint32_t u32x2;

#define MFMA16(a,b,c) __builtin_amdgcn_mfma_f32_16x16x32_bf16((a),(b),(c),0,0,0)

__device__ __forceinline__ uint16_t f2bf(float f){
  uint32_t u = __float_as_uint(f);
  return (uint16_t)((u + 0x7FFFu + ((u >> 16) & 1u)) >> 16);   // RNE
}

// packed f32x2 -> bf16x2 (RNE), single instruction
__device__ __forceinline__ uint32_t pk_bf16(float lo, float hi){
  uint32_t r; asm("v_cvt_pk_bf16_f32 %0, %1, %2" : "=v"(r) : "v"(lo), "v"(hi)); return r;
}

__device__ __forceinline__ float fast_exp2(float x){
  float r; asm("v_exp_f32 %0, %1" : "=v"(r) : "v"(x)); return r;
}

// async global->LDS, 16B per lane; LDS dest must be (wave-uniform base + lane*16)
__device__ __forceinline__ void gload16(const uint16_t* g, uint16_t* l){
  __builtin_amdgcn_global_load_lds((const __attribute__((address_space(1))) uint32_t*)g,
                                   (__attribute__((address_space(3))) uint32_t*)l, 16, 0, 0);
}

// ---------- prep: x->bf16 (blocks 0..4095) + bias transpose (blocks 4096..4351) ----------
__global__ void k_cvtb(const float* __restrict__ in, uint16_t* __restrict__ out,
                       const float* __restrict__ btab, float* __restrict__ bias_t){
  const int bx = blockIdx.x;
  if (bx < 4096){
    const size_t i = (size_t)(bx*256 + threadIdx.x) * 4;
    const f32x4 v = *(const f32x4*)(in + i);
    u32x2 pk = {pk_bf16(v[0], v[1]), pk_bf16(v[2], v[3])};
    *(u32x2*)(out + i) = pk;
  } else {
    const int i = (bx - 4096)*256 + threadIdx.x;
    if (i < 4095*16) bias_t[(i & 15)*4096 + (i >> 4)] = btab[i] * 1.4426950408889634f;
  }
}

__global__ void k_tcvt(const float* __restrict__ in, uint16_t* __restrict__ out, int K, int N){
  __shared__ float tile[64][65];
  const int k0 = blockIdx.y*64, n0 = blockIdx.x*64;
  const int tc = threadIdx.x & 63, tr = threadIdx.x >> 6;
  #pragma unroll
  for (int p=0;p<16;p++){ int r = p*4 + tr; tile[r][tc] = in[(size_t)(k0+r)*N + n0 + tc]; }
  __syncthreads();
  #pragma unroll
  for (int p=0;p<16;p++){ int r = p*4 + tr; out[(size_t)(n0+r)*K + k0 + tc] = f2bf(tile[tc][r]); }
}

// ---------- GEMM0: C(4096 x 3072) = A * Bt^T, BM=BN=128, BK=64; q/k/v scatter ----------
// Single-buffer (r11 form): r13 measured the double-buffer variant at +8us — the
// 2-blocks/CU implicit wave overlap already hides the staging drain.
__global__ __launch_bounds__(256, 2) void k_gemm(
    const uint16_t* __restrict__ A, const uint16_t* __restrict__ Bt,
    const float* __restrict__ bias,
    uint16_t* __restrict__ qo, uint16_t* __restrict__ ko, uint16_t* __restrict__ vto)
{
  __shared__ __align__(16) uint16_t at[128*64];   // [row 128B = 8 chunks], chunk ^= row&7
  __shared__ __align__(16) uint16_t bt[128*64];
  const int tid = threadIdx.x;
  const int lane = tid & 63, w = tid >> 6;
  const int g = lane >> 4, li = lane & 15;
  const int wr = w >> 1, wc = w & 1;
  const int m0 = blockIdx.y * 128, n0 = blockIdx.x * 128;

  f32x4 acc[4][4] = {};

  const int srow = tid >> 3;
  const int scg  = (tid & 7) ^ (srow & 7);

  for (int kt_ = 0; kt_ < 16; kt_++){
    const int kk = kt_*64;
    __syncthreads();
    #pragma unroll
    for (int j = 0; j < 4; j++){
      gload16(A  + (size_t)(m0 + j*32 + srow)*1024 + kk + scg*8, at + (j*256+tid)*8);
      gload16(Bt + (size_t)(n0 + j*32 + srow)*1024 + kk + scg*8, bt + (j*256+tid)*8);
    }
    asm volatile("s_waitcnt vmcnt(0)" ::: "memory");
    __syncthreads();

    bf16x8 af[2][4], bfr[2][4];
    #pragma unroll
    for (int mi=0; mi<4; mi++){
      int row = wr*64 + mi*16 + li, sw = row & 7;
      af[0][mi] = *(const bf16x8*)(at + row*64 + ((g     ^ sw)*8));
      af[1][mi] = *(const bf16x8*)(at + row*64 + (((4+g) ^ sw)*8));
    }
    #pragma unroll
    for (int ni=0; ni<4; ni++){
      int row = wc*64 + ni*16 + li, sw = row & 7;
      bfr[0][ni] = *(const bf16x8*)(bt + row*64 + ((g     ^ sw)*8));
      bfr[1][ni] = *(const bf16x8*)(bt + row*64 + (((4+g) ^ sw)*8));
    }
    #pragma unroll
    for (int s=0; s<2; s++)
      #pragma unroll
      for (int mi=0; mi<4; mi++)
        #pragma unroll
        for (int ni=0; ni<4; ni++)
          acc[mi][ni] = MFMA16(af[s][mi], bfr[s][ni], acc[mi][ni]);
  }

  #pragma unroll
  for (int ni=0; ni<4; ni++){
    const int c = n0 + wc*64 + ni*16 + li;
    const float bv = bias[c];
    const int which = c >> 10, cc = c & 1023;
    const int h = cc >> 6, d = cc & 63;
    #pragma unroll
    for (int mi=0; mi<4; mi++){
      const int trow = m0 + wr*64 + mi*16 + g*4;
      const int b_ = trow >> 11, lcl = trow & 2047;
      const f32x4 v4 = acc[mi][ni];
      if (which == 0){
        uint16_t* dst = qo + (((size_t)(b_*16 + h)*2048 + lcl)*64 + d);
        #pragma unroll
        for (int r=0;r<4;r++) dst[(size_t)r*64] = f2bf((v4[r] + bv) * 0.18033688011112042f);
      } else if (which == 1){
        uint16_t* dst = ko + (((size_t)(b_*16 + h)*2048 + lcl)*64 + d);
        #pragma unroll
        for (int r=0;r<4;r++) dst[(size_t)r*64] = f2bf(v4[r] + bv);
      } else {
        u32x2 pk = {pk_bf16(v4[0]+bv, v4[1]+bv), pk_bf16(v4[2]+bv, v4[3]+bv)};
        *(u32x2*)(vto + (((size_t)(b_*16 + h)*64 + d)*2048 + lcl)) = pk;
      }
    }
  }
}

// ---------- GEMM1 (proj): C(4096 x 1024) = A * Bt^T, BM=128, BN=64 -> 512 blocks ----------
__global__ __launch_bounds__(256, 2) void k_gemm2(
    const uint16_t* __restrict__ A, const uint16_t* __restrict__ Bt,
    const float* __restrict__ bias, float* __restrict__ outf)
{
  __shared__ __align__(16) uint16_t at[128*64];   // 16KB
  __shared__ __align__(16) uint16_t bt[64*64];    // 8KB
  const int tid = threadIdx.x;
  const int lane = tid & 63, w = tid >> 6;
  const int g = lane >> 4, li = lane & 15;
  const int wr = w >> 1, wc = w & 1;
  const int m0 = blockIdx.y * 128, n0 = blockIdx.x * 64;

  f32x4 acc[4][2] = {};
  const int srow = tid >> 3;
  const int scg  = (tid & 7) ^ (srow & 7);

  for (int kt_ = 0; kt_ < 16; kt_++){
    const int kk = kt_*64;
    __syncthreads();
    #pragma unroll
    for (int j = 0; j < 4; j++)
      gload16(A  + (size_t)(m0 + j*32 + srow)*1024 + kk + scg*8, at + (j*256+tid)*8);
    #pragma unroll
    for (int j = 0; j < 2; j++)
      gload16(Bt + (size_t)(n0 + j*32 + srow)*1024 + kk + scg*8, bt + (j*256+tid)*8);
    asm volatile("s_waitcnt vmcnt(0)" ::: "memory");
    __syncthreads();

    bf16x8 af[2][4], bfr[2][2];
    #pragma unroll
    for (int mi=0; mi<4; mi++){
      int row = wr*64 + mi*16 + li, sw = row & 7;
      af[0][mi] = *(const bf16x8*)(at + row*64 + ((g     ^ sw)*8));
      af[1][mi] = *(const bf16x8*)(at + row*64 + (((4+g) ^ sw)*8));
    }
    #pragma unroll
    for (int ni=0; ni<2; ni++){
      int row = wc*32 + ni*16 + li, sw = row & 7;
      bfr[0][ni] = *(const bf16x8*)(bt + row*64 + ((g     ^ sw)*8));
      bfr[1][ni] = *(const bf16x8*)(bt + row*64 + (((4+g) ^ sw)*8));
    }
    #pragma unroll
    for (int s=0; s<2; s++)
      #pragma unroll
      for (int mi=0; mi<4; mi++)
        #pragma unroll
        for (int ni=0; ni<2; ni++)
          acc[mi][ni] = MFMA16(af[s][mi], bfr[s][ni], acc[mi][ni]);
  }

  #pragma unroll
  for (int ni=0; ni<2; ni++){
    const int c = n0 + wc*32 + ni*16 + li;
    const float bv = bias[c];
    #pragma unroll
    for (int mi=0; mi<4; mi++){
      const int trow = m0 + wr*64 + mi*16 + g*4;
      float* dst = outf + (size_t)trow*1024 + c;
      const f32x4 v4 = acc[mi][ni];
      #pragma unroll
      for (int r=0;r<4;r++) dst[(size_t)r*1024] = v4[r] + bv;
    }
  }
}

// ---------- flash attention: 4 waves x 32 q (QBLK=128), KVBLK=64, NO split ----------
// Non-split (r5 loop shape) + all proven refinements: single-set 5-window diagonal
// bias (vmcnt 9/5 discipline), reg diet, ones-MFMA rowsum, shuffle-free defer-max,
// setprio. Split removed: its 2.6us attn gain cost ~6us of k_merge (r11 vs r5 ledger).
// NOTE: launch_bounds stays (256,2) — (256,4) spills catastrophically (r8).
__device__ __forceinline__ void attn_tile(
    int t, bool last, int tid, int g, int li, int srow, int scg,
    const uint16_t* kbase, const uint16_t* vbase, const float* bb,
    const uint16_t* ktc, uint16_t* ktn, const uint16_t* vtc, uint16_t* vtn, uint16_t* pl,
    const bf16x8 (&qf)[2][2], bf16x8 ones,
    f32x4 (&o)[4][2], f32x4 (&o4)[2], float& mrun0, float& mrun1)
{
  const int kv0 = t*64;

  // bias for THIS tile: 5 diagonal windows; bv[c=0][mf]=bv5[mf+1], bv[c=1][mf]=bv5[mf]
  f32x4 bv5[5];
  #pragma unroll
  for (int j=0;j<5;j++)
    bv5[j] = *(const f32x4u*)(bb + kv0 + (j-1)*16 + g*4 - li);
  asm volatile("" ::: "memory");                           // pin issue order: bias -> staging

  if (!last){
    const int kv1 = kv0 + 64;
    gload16(kbase + (size_t)(kv1+srow)*64 + scg*8,         ktn + tid*8);
    gload16(kbase + (size_t)(kv1+srow+32)*64 + scg*8,      ktn + 2048 + tid*8);
    gload16(vbase + (size_t)srow*2048 + kv1 + scg*8,       vtn + tid*8);
    gload16(vbase + (size_t)(srow+32)*2048 + kv1 + scg*8,  vtn + 2048 + tid*8);
    // queue (old->new): stage(t)4, bias(t)5, stage(t+1)4 = 13 outstanding
    asm volatile("s_waitcnt vmcnt(9)" ::: "memory");       // retire stage(t); keep bias+stage(t+1)
  } else {
    asm volatile("s_waitcnt vmcnt(5)" ::: "memory");       // retire stage(t); keep bias(t)
  }
  __builtin_amdgcn_s_barrier();                            // A: tile t ready

  // S^T(64kv x 32q) = K * Q^T   (K-frags shared across both q col-blocks)
  f32x4 sa[4][2];
  __builtin_amdgcn_s_setprio(1);
  #pragma unroll
  for (int mf=0; mf<4; mf++){
    const int row = mf*16 + li, sw = row & 7;
    bf16x8 a0 = *(const bf16x8*)(ktc + row*64 + ((g     ^ sw)*8));
    bf16x8 a1 = *(const bf16x8*)(ktc + row*64 + (((4+g) ^ sw)*8));
    #pragma unroll
    for (int c=0;c<2;c++){
      f32x4 cfr = {};
      cfr = MFMA16(a0, qf[c][0], cfr);
      cfr = MFMA16(a1, qf[c][1], cfr);
      sa[mf][c] = cfr;
    }
  }
  __builtin_amdgcn_s_setprio(0);

  // bias add + lane-local max (q = c*16+li; kv = mf*16+g*4+r)
  float t0 = -__builtin_inff(), t1 = -__builtin_inff();
  #pragma unroll
  for (int mf=0; mf<4; mf++){
    sa[mf][0] += bv5[mf+1];
    sa[mf][1] += bv5[mf];
    #pragma unroll
    for (int r=0; r<4; r++){
      t0 = fmaxf(t0, sa[mf][0][r]);
      t1 = fmaxf(t1, sa[mf][1][r]);
    }
  }

  // defer-max (T13): common path has NO cross-lane ops; rare path full reduce.
  const int ok = (t0 <= mrun0 + 8.f) && (t1 <= mrun1 + 8.f);
  if (!__all(ok)){
    float r0 = t0, r1 = t1;
    r0 = fmaxf(r0, __shfl_xor(r0, 16)); r0 = fmaxf(r0, __shfl_xor(r0, 32));
    r1 = fmaxf(r1, __shfl_xor(r1, 16)); r1 = fmaxf(r1, __shfl_xor(r1, 32));
    const float mn0 = fmaxf(mrun0, r0), mn1 = fmaxf(mrun1, r1);
    const float a0 = fast_exp2(mrun0 - mn0), a1 = fast_exp2(mrun1 - mn1);
    #pragma unroll
    for (int mf=0; mf<4; mf++){ o[mf][0] *= a0; o[mf][1] *= a1; }
    o4[0] *= a0; o4[1] *= a1;
    mrun0 = mn0; mrun1 = mn1;
  }

  // V fragments (shared by both c-blocks)
  bf16x8 av[2][4];
  #pragma unroll
  for (int s=0; s<2; s++)
    #pragma unroll
    for (int mf=0; mf<4; mf++){
      const int row = mf*16 + li, sw = row & 7;
      av[s][mf] = *(const bf16x8*)(vtc + row*64 + (((4*s+g) ^ sw)*8));
    }

  // per c-block: P = exp2(S-m) -> bf16 -> P-slab (REUSED across c: 2KB/wave) -> PV
  const int swp2 = 2*(li & 7);
  #pragma unroll
  for (int c=0;c<2;c++){
    const float mr = c ? mrun1 : mrun0;
    #pragma unroll
    for (int mf=0; mf<4; mf++){
      float p0 = fast_exp2(sa[mf][c][0] - mr);
      float p1 = fast_exp2(sa[mf][c][1] - mr);
      float p2 = fast_exp2(sa[mf][c][2] - mr);
      float p3 = fast_exp2(sa[mf][c][3] - mr);
      u32x2 pk = {pk_bf16(p0,p1), pk_bf16(p2,p3)};
      *(u32x2*)(pl + li*64 + (((4*mf+g) ^ swp2)*4)) = pk;
    }
    __builtin_amdgcn_s_setprio(1);
    #pragma unroll
    for (int s=0; s<2; s++){
      bf16x8 pb = *(const bf16x8*)(pl + li*64 + (((8*s+2*g) ^ swp2)*4));
      o4[c] = MFMA16(ones, pb, o4[c]);
      #pragma unroll
      for (int mf=0; mf<4; mf++)
        o[mf][c] = MFMA16(av[s][mf], pb, o[mf][c]);
    }
    __builtin_amdgcn_s_setprio(0);
  }
  __builtin_amdgcn_s_barrier();                            // B: done reading tile t
}

__global__ __launch_bounds__(256, 2) void k_attn(
    const uint16_t* __restrict__ qg, const uint16_t* __restrict__ kg,
    const uint16_t* __restrict__ vg, const float* __restrict__ biast,
    uint16_t* __restrict__ outp)
{
  __shared__ __align__(16) uint16_t kt[2][64*64];  // K tile [kv][d], 16B-chunk ^= row&7 (16KB)
  __shared__ __align__(16) uint16_t vt[2][64*64];  // V^T tile [d][kv], same swizzle   (16KB)
  __shared__ __align__(16) uint16_t pt[4][16*64];  // per-wave P^T [16q][64kv], reused  (8KB)
  const int tid = threadIdx.x;
  const int lane = tid & 63, w = tid >> 6;         // 4 waves
  const int g = lane >> 4, li = lane & 15;
  const int bh = blockIdx.y, h = bh & 15, b_ = bh >> 4;
  const int qw = blockIdx.x*128 + w*32;            // wave's q base (32 rows)

  bf16x8 qf[2][2];
  #pragma unroll
  for (int c=0;c<2;c++){
    const uint16_t* qp = qg + ((size_t)bh*2048 + qw + c*16 + li)*64 + g*8;
    qf[c][0] = *(const bf16x8*)(qp);
    qf[c][1] = *(const bf16x8*)(qp + 32);
  }
  bf16x8 ones = (bf16x8)(short)0;                  // A-frag: row 0 = 1.0, rows 1-15 = 0
  if (li == 0){ const short v = (short)0x3F80; ones = (bf16x8){v,v,v,v,v,v,v,v}; }

  f32x4 o[4][2] = {};
  f32x4 o4[2] = {};
  float mrun0 = -__builtin_inff(), mrun1 = -__builtin_inff();

  const uint16_t* kbase = kg + (size_t)bh*(2048*64);
  const uint16_t* vbase = vg + (size_t)bh*(64*2048);
  const int srow = tid >> 3;                       // 0..31
  const int scg  = (tid & 7) ^ (srow & 7);
  const float* bb = biast + h*4096 + 2047 - qw;    // + kv - (c*16+li)
  uint16_t* pl = &pt[w][0];

  // prologue: stage tile 0
  gload16(kbase + (size_t)srow*64 + scg*8,         &kt[0][tid*8]);
  gload16(kbase + (size_t)(srow+32)*64 + scg*8,    &kt[0][2048 + tid*8]);
  gload16(vbase + (size_t)srow*2048 + scg*8,       &vt[0][tid*8]);
  gload16(vbase + (size_t)(srow+32)*2048 + scg*8,  &vt[0][2048 + tid*8]);

  for (int tt = 0; tt < 32; tt += 2){
    attn_tile(tt,   false,    tid, g, li, srow, scg, kbase, vbase, bb,
              &kt[0][0], &kt[1][0], &vt[0][0], &vt[1][0], pl,
              qf, ones, o, o4, mrun0, mrun1);
    attn_tile(tt+1, tt == 30, tid, g, li, srow, scg, kbase, vbase, bb,
              &kt[1][0], &kt[0][0], &vt[1][0], &vt[0][0], pl,
              qf, ones, o, o4, mrun0, mrun1);
  }

  // row sums in o4[c] reg 0 of g=0 lanes; broadcast; write normalized O
  const float ls0 = __shfl(o4[0][0], li);
  const float ls1 = __shfl(o4[1][0], li);
  const float inv0 = 1.0f / ls0, inv1 = 1.0f / ls1;
  #pragma unroll
  for (int c=0;c<2;c++){
    const float inv = c ? inv1 : inv0;
    const size_t token = (size_t)b_*2048 + qw + c*16 + li;
    #pragma unroll
    for (int mf=0; mf<4; mf++){
      u32x2 pk = {pk_bf16(o[mf][c][0]*inv, o[mf][c][1]*inv),
                  pk_bf16(o[mf][c][2]*inv, o[mf][c][3]*inv)};
      *(u32x2*)(outp + token*1024 + h*64 + mf*16 + g*4) = pk;
    }
  }
}

// ---------- launch ----------
extern "C" void kernel_launch(void* const* d_in, const int* in_sizes, int n_in,
                              void* d_out, int out_size, void* d_ws, size_t ws_size,
                              hipStream_t stream)
{
  const float* x      = (const float*)d_in[0];
  const float* qkv_w  = (const float*)d_in[1];
  const float* qkv_b  = (const float*)d_in[2];
  const float* proj_w = (const float*)d_in[3];
  const float* proj_b = (const float*)d_in[4];
  const float* btab   = (const float*)d_in[5];
  float* out = (float*)d_out;

  char* p = (char*)d_ws;
  uint16_t* x_bf    = (uint16_t*)(p);
  uint16_t* qkv_wt  = (uint16_t*)(p + 8388608);
  uint16_t* proj_wt = (uint16_t*)(p + 14680064);
  uint16_t* q_buf   = (uint16_t*)(p + 16777216);   // (b,h,l,d) bf16, prescaled
  uint16_t* k_buf   = (uint16_t*)(p + 25165824);   // (b,h,l,d) bf16
  uint16_t* vt_buf  = (uint16_t*)(p + 33554432);   // (b,h,d,l) bf16
  uint16_t* ao_buf  = (uint16_t*)(p + 41943040);   // attn out (tokens x 1024) bf16
  float*    bias_t  = (float*)   (p + 50331648);   // 16 x 4096 f32, *log2e

  k_cvtb <<<dim3(4352),  dim3(256), 0, stream>>>(x, x_bf, btab, bias_t);
  k_tcvt <<<dim3(48,16), dim3(256), 0, stream>>>(qkv_w,  qkv_wt,  1024, 3072);
  k_tcvt <<<dim3(16,16), dim3(256), 0, stream>>>(proj_w, proj_wt, 1024, 1024);

  k_gemm   <<<dim3(24,32), dim3(256), 0, stream>>>(x_bf, qkv_wt, qkv_b, q_buf, k_buf, vt_buf);
  k_attn   <<<dim3(16,32), dim3(256), 0, stream>>>(q_buf, k_buf, vt_buf, bias_t, ao_buf);
  k_gemm2  <<<dim3(16,32), dim3(256), 0, stream>>>(ao_buf, proj_wt, proj_b, out);
}

// Round 15
// 118.033 us; speedup vs baseline: 1.3298x; 1.0122x over previous
//
#include <hip/hip_runtime.h>
#include <stdint.h>

// ---------- types & helpers ----------
typedef __attribute__((ext_vector_type(4))) float    f32x4;
typedef f32x4 __attribute__((aligned(4)))   f32x4u;  // 4B-aligned vector load (global allows it)
typedef __attribute__((ext_vector_type(8))) short    bf16x8;   // 8 bf16 (4 VGPRs) — MFMA operand
typedef __attribute__((ext_vector_type(2))) uint32_t u32x2;

#define MFMA16(a,b,c) __builtin_amdgcn_mfma_f32_16x16x32_bf16((a),(b),(c),0,0,0)

__device__ __forceinline__ uint16_t f2bf(float f){
  uint32_t u = __float_as_uint(f);
  return (uint16_t)((u + 0x7FFFu + ((u >> 16) & 1u)) >> 16);   // RNE
}

// packed f32x2 -> bf16x2 (RNE), single instruction
__device__ __forceinline__ uint32_t pk_bf16(float lo, float hi){
  uint32_t r; asm("v_cvt_pk_bf16_f32 %0, %1, %2" : "=v"(r) : "v"(lo), "v"(hi)); return r;
}

__device__ __forceinline__ float fast_exp2(float x){
  float r; asm("v_exp_f32 %0, %1" : "=v"(r) : "v"(x)); return r;
}

// async global->LDS, 16B per lane; LDS dest must be (wave-uniform base + lane*16)
__device__ __forceinline__ void gload16(const uint16_t* g, uint16_t* l){
  __builtin_amdgcn_global_load_lds((const __attribute__((address_space(1))) uint32_t*)g,
                                   (__attribute__((address_space(3))) uint32_t*)l, 16, 0, 0);
}

// ---------- fused prep (single launch, 5376 blocks) ----------
// blocks [0,4096):   x fp32 -> bf16
// blocks [4096,4352): bias_table transpose (16 x 4096, *log2e)
// blocks [4352,5120): qkv_w transpose-convert (1024x3072 -> 3072x1024 bf16)
// blocks [5120,5376): proj_w transpose-convert (1024x1024 -> 1024x1024 bf16)
__global__ void k_prep(const float* __restrict__ x, uint16_t* __restrict__ x_bf,
                       const float* __restrict__ btab, float* __restrict__ bias_t,
                       const float* __restrict__ qkv_w, uint16_t* __restrict__ qkv_wt,
                       const float* __restrict__ proj_w, uint16_t* __restrict__ proj_wt){
  __shared__ float tile[64][65];
  const int bx = blockIdx.x;
  if (bx < 4096){
    const size_t i = (size_t)(bx*256 + threadIdx.x) * 4;
    const f32x4 v = *(const f32x4*)(x + i);
    u32x2 pk = {pk_bf16(v[0], v[1]), pk_bf16(v[2], v[3])};
    *(u32x2*)(x_bf + i) = pk;
    return;
  }
  if (bx < 4352){
    const int i = (bx - 4096)*256 + threadIdx.x;
    if (i < 4095*16) bias_t[(i & 15)*4096 + (i >> 4)] = btab[i] * 1.4426950408889634f;
    return;
  }
  const float* in;  uint16_t* out;  int K, N, n0, k0;
  if (bx < 5120){
    const int b2 = bx - 4352;                        // 768 = 48 x 16
    in = qkv_w; out = qkv_wt; K = 1024; N = 3072;
    n0 = (b2 % 48)*64; k0 = (b2 / 48)*64;
  } else {
    const int b3 = bx - 5120;                        // 256 = 16 x 16
    in = proj_w; out = proj_wt; K = 1024; N = 1024;
    n0 = (b3 % 16)*64; k0 = (b3 / 16)*64;
  }
  const int tc = threadIdx.x & 63, tr = threadIdx.x >> 6;
  #pragma unroll
  for (int p=0;p<16;p++){ int r = p*4 + tr; tile[r][tc] = in[(size_t)(k0+r)*N + n0 + tc]; }
  __syncthreads();
  #pragma unroll
  for (int p=0;p<16;p++){ int r = p*4 + tr; out[(size_t)(n0+r)*K + k0 + tc] = f2bf(tile[tc][r]); }
}

// ---------- GEMM0: C(4096 x 3072) = A * Bt^T, BM=64, BN=128, BK=64; q/k/v scatter ----------
// BM 128->64: grid 768->1536 blocks. At 2 blocks/CU (512 co-resident) the old grid ran
// 1.5 "block waves" (last 256 blocks on a half-idle machine); 1536 divides evenly.
// acc halves to [4][2] (32 VGPR). B-panel re-reads double but B=6.3MB is L2/L3-resident.
__global__ __launch_bounds__(256, 2) void k_gemm(
    const uint16_t* __restrict__ A, const uint16_t* __restrict__ Bt,
    const float* __restrict__ bias,
    uint16_t* __restrict__ qo, uint16_t* __restrict__ ko, uint16_t* __restrict__ vto)
{
  __shared__ __align__(16) uint16_t at[64*64];    // 8KB, [row 128B = 8 chunks], chunk ^= row&7
  __shared__ __align__(16) uint16_t bt[128*64];   // 16KB
  const int tid = threadIdx.x;
  const int lane = tid & 63, wc = tid >> 6;       // 4 column-waves
  const int g = lane >> 4, li = lane & 15;
  const int m0 = blockIdx.y * 64, n0 = blockIdx.x * 128;

  f32x4 acc[4][2] = {};

  const int srow = tid >> 3;                       // 0..31
  const int scg  = (tid & 7) ^ (srow & 7);

  for (int kt_ = 0; kt_ < 16; kt_++){
    const int kk = kt_*64;
    __syncthreads();
    #pragma unroll
    for (int j = 0; j < 2; j++)
      gload16(A  + (size_t)(m0 + j*32 + srow)*1024 + kk + scg*8, at + (j*256+tid)*8);
    #pragma unroll
    for (int j = 0; j < 4; j++)
      gload16(Bt + (size_t)(n0 + j*32 + srow)*1024 + kk + scg*8, bt + (j*256+tid)*8);
    asm volatile("s_waitcnt vmcnt(0)" ::: "memory");
    __syncthreads();

    bf16x8 af[2][4], bfr[2][2];
    #pragma unroll
    for (int mi=0; mi<4; mi++){
      int row = mi*16 + li, sw = row & 7;
      af[0][mi] = *(const bf16x8*)(at + row*64 + ((g     ^ sw)*8));
      af[1][mi] = *(const bf16x8*)(at + row*64 + (((4+g) ^ sw)*8));
    }
    #pragma unroll
    for (int ni=0; ni<2; ni++){
      int row = wc*32 + ni*16 + li, sw = row & 7;
      bfr[0][ni] = *(const bf16x8*)(bt + row*64 + ((g     ^ sw)*8));
      bfr[1][ni] = *(const bf16x8*)(bt + row*64 + (((4+g) ^ sw)*8));
    }
    #pragma unroll
    for (int s=0; s<2; s++)
      #pragma unroll
      for (int mi=0; mi<4; mi++)
        #pragma unroll
        for (int ni=0; ni<2; ni++)
          acc[mi][ni] = MFMA16(af[s][mi], bfr[s][ni], acc[mi][ni]);
  }

  #pragma unroll
  for (int ni=0; ni<2; ni++){
    const int c = n0 + wc*32 + ni*16 + li;
    const float bv = bias[c];
    const int which = c >> 10, cc = c & 1023;
    const int h = cc >> 6, d = cc & 63;
    #pragma unroll
    for (int mi=0; mi<4; mi++){
      const int trow = m0 + mi*16 + g*4;
      const int b_ = trow >> 11, lcl = trow & 2047;
      const f32x4 v4 = acc[mi][ni];
      if (which == 0){
        uint16_t* dst = qo + (((size_t)(b_*16 + h)*2048 + lcl)*64 + d);
        #pragma unroll
        for (int r=0;r<4;r++) dst[(size_t)r*64] = f2bf((v4[r] + bv) * 0.18033688011112042f);
      } else if (which == 1){
        uint16_t* dst = ko + (((size_t)(b_*16 + h)*2048 + lcl)*64 + d);
        #pragma unroll
        for (int r=0;r<4;r++) dst[(size_t)r*64] = f2bf(v4[r] + bv);
      } else {
        u32x2 pk = {pk_bf16(v4[0]+bv, v4[1]+bv), pk_bf16(v4[2]+bv, v4[3]+bv)};
        *(u32x2*)(vto + (((size_t)(b_*16 + h)*64 + d)*2048 + lcl)) = pk;
      }
    }
  }
}

// ---------- GEMM1 (proj): C(4096 x 1024) = A * Bt^T, BM=128, BN=64 -> 512 blocks ----------
__global__ __launch_bounds__(256, 2) void k_gemm2(
    const uint16_t* __restrict__ A, const uint16_t* __restrict__ Bt,
    const float* __restrict__ bias, float* __restrict__ outf)
{
  __shared__ __align__(16) uint16_t at[128*64];   // 16KB
  __shared__ __align__(16) uint16_t bt[64*64];    // 8KB
  const int tid = threadIdx.x;
  const int lane = tid & 63, w = tid >> 6;
  const int g = lane >> 4, li = lane & 15;
  const int wr = w >> 1, wc = w & 1;
  const int m0 = blockIdx.y * 128, n0 = blockIdx.x * 64;

  f32x4 acc[4][2] = {};
  const int srow = tid >> 3;
  const int scg  = (tid & 7) ^ (srow & 7);

  for (int kt_ = 0; kt_ < 16; kt_++){
    const int kk = kt_*64;
    __syncthreads();
    #pragma unroll
    for (int j = 0; j < 4; j++)
      gload16(A  + (size_t)(m0 + j*32 + srow)*1024 + kk + scg*8, at + (j*256+tid)*8);
    #pragma unroll
    for (int j = 0; j < 2; j++)
      gload16(Bt + (size_t)(n0 + j*32 + srow)*1024 + kk + scg*8, bt + (j*256+tid)*8);
    asm volatile("s_waitcnt vmcnt(0)" ::: "memory");
    __syncthreads();

    bf16x8 af[2][4], bfr[2][2];
    #pragma unroll
    for (int mi=0; mi<4; mi++){
      int row = wr*64 + mi*16 + li, sw = row & 7;
      af[0][mi] = *(const bf16x8*)(at + row*64 + ((g     ^ sw)*8));
      af[1][mi] = *(const bf16x8*)(at + row*64 + (((4+g) ^ sw)*8));
    }
    #pragma unroll
    for (int ni=0; ni<2; ni++){
      int row = wc*32 + ni*16 + li, sw = row & 7;
      bfr[0][ni] = *(const bf16x8*)(bt + row*64 + ((g     ^ sw)*8));
      bfr[1][ni] = *(const bf16x8*)(bt + row*64 + (((4+g) ^ sw)*8));
    }
    #pragma unroll
    for (int s=0; s<2; s++)
      #pragma unroll
      for (int mi=0; mi<4; mi++)
        #pragma unroll
        for (int ni=0; ni<2; ni++)
          acc[mi][ni] = MFMA16(af[s][mi], bfr[s][ni], acc[mi][ni]);
  }

  #pragma unroll
  for (int ni=0; ni<2; ni++){
    const int c = n0 + wc*32 + ni*16 + li;
    const float bv = bias[c];
    #pragma unroll
    for (int mi=0; mi<4; mi++){
      const int trow = m0 + wr*64 + mi*16 + g*4;
      float* dst = outf + (size_t)trow*1024 + c;
      const f32x4 v4 = acc[mi][ni];
      #pragma unroll
      for (int r=0;r<4;r++) dst[(size_t)r*1024] = v4[r] + bv;
    }
  }
}

// ---------- flash attention: 4 waves x 32 q (QBLK=128), KVBLK=64 (byte-identical to r14) ----------
// NOTE: launch_bounds stays (256,2) — (256,4) spills catastrophically (r8).
__device__ __forceinline__ void attn_tile(
    int t, bool last, int tid, int g, int li, int srow, int scg,
    const uint16_t* kbase, const uint16_t* vbase, const float* bb,
    const uint16_t* ktc, uint16_t* ktn, const uint16_t* vtc, uint16_t* vtn, uint16_t* pl,
    const bf16x8 (&qf)[2][2], bf16x8 ones,
    f32x4 (&o)[4][2], f32x4 (&o4)[2], float& mrun0, float& mrun1)
{
  const int kv0 = t*64;

  // bias for THIS tile: 5 diagonal windows; bv[c=0][mf]=bv5[mf+1], bv[c=1][mf]=bv5[mf]
  f32x4 bv5[5];
  #pragma unroll
  for (int j=0;j<5;j++)
    bv5[j] = *(const f32x4u*)(bb + kv0 + (j-1)*16 + g*4 - li);
  asm volatile("" ::: "memory");                           // pin issue order: bias -> staging

  if (!last){
    const int kv1 = kv0 + 64;
    gload16(kbase + (size_t)(kv1+srow)*64 + scg*8,         ktn + tid*8);
    gload16(kbase + (size_t)(kv1+srow+32)*64 + scg*8,      ktn + 2048 + tid*8);
    gload16(vbase + (size_t)srow*2048 + kv1 + scg*8,       vtn + tid*8);
    gload16(vbase + (size_t)(srow+32)*2048 + kv1 + scg*8,  vtn + 2048 + tid*8);
    // queue (old->new): stage(t)4, bias(t)5, stage(t+1)4 = 13 outstanding
    asm volatile("s_waitcnt vmcnt(9)" ::: "memory");       // retire stage(t); keep bias+stage(t+1)
  } else {
    asm volatile("s_waitcnt vmcnt(5)" ::: "memory");       // retire stage(t); keep bias(t)
  }
  __builtin_amdgcn_s_barrier();                            // A: tile t ready

  // S^T(64kv x 32q) = K * Q^T   (K-frags shared across both q col-blocks)
  f32x4 sa[4][2];
  __builtin_amdgcn_s_setprio(1);
  #pragma unroll
  for (int mf=0; mf<4; mf++){
    const int row = mf*16 + li, sw = row & 7;
    bf16x8 a0 = *(const bf16x8*)(ktc + row*64 + ((g     ^ sw)*8));
    bf16x8 a1 = *(const bf16x8*)(ktc + row*64 + (((4+g) ^ sw)*8));
    #pragma unroll
    for (int c=0;c<2;c++){
      f32x4 cfr = {};
      cfr = MFMA16(a0, qf[c][0], cfr);
      cfr = MFMA16(a1, qf[c][1], cfr);
      sa[mf][c] = cfr;
    }
  }
  __builtin_amdgcn_s_setprio(0);

  // bias add + lane-local max (q = c*16+li; kv = mf*16+g*4+r)
  float t0 = -__builtin_inff(), t1 = -__builtin_inff();
  #pragma unroll
  for (int mf=0; mf<4; mf++){
    sa[mf][0] += bv5[mf+1];
    sa[mf][1] += bv5[mf];
    #pragma unroll
    for (int r=0; r<4; r++){
      t0 = fmaxf(t0, sa[mf][0][r]);
      t1 = fmaxf(t1, sa[mf][1][r]);
    }
  }

  // defer-max (T13): common path has NO cross-lane ops; rare path full reduce.
  const int ok = (t0 <= mrun0 + 8.f) && (t1 <= mrun1 + 8.f);
  if (!__all(ok)){
    float r0 = t0, r1 = t1;
    r0 = fmaxf(r0, __shfl_xor(r0, 16)); r0 = fmaxf(r0, __shfl_xor(r0, 32));
    r1 = fmaxf(r1, __shfl_xor(r1, 16)); r1 = fmaxf(r1, __shfl_xor(r1, 32));
    const float mn0 = fmaxf(mrun0, r0), mn1 = fmaxf(mrun1, r1);
    const float a0 = fast_exp2(mrun0 - mn0), a1 = fast_exp2(mrun1 - mn1);
    #pragma unroll
    for (int mf=0; mf<4; mf++){ o[mf][0] *= a0; o[mf][1] *= a1; }
    o4[0] *= a0; o4[1] *= a1;
    mrun0 = mn0; mrun1 = mn1;
  }

  // V fragments (shared by both c-blocks)
  bf16x8 av[2][4];
  #pragma unroll
  for (int s=0; s<2; s++)
    #pragma unroll
    for (int mf=0; mf<4; mf++){
      const int row = mf*16 + li, sw = row & 7;
      av[s][mf] = *(const bf16x8*)(vtc + row*64 + (((4*s+g) ^ sw)*8));
    }

  // per c-block: P = exp2(S-m) -> bf16 -> P-slab (REUSED across c: 2KB/wave) -> PV
  const int swp2 = 2*(li & 7);
  #pragma unroll
  for (int c=0;c<2;c++){
    const float mr = c ? mrun1 : mrun0;
    #pragma unroll
    for (int mf=0; mf<4; mf++){
      float p0 = fast_exp2(sa[mf][c][0] - mr);
      float p1 = fast_exp2(sa[mf][c][1] - mr);
      float p2 = fast_exp2(sa[mf][c][2] - mr);
      float p3 = fast_exp2(sa[mf][c][3] - mr);
      u32x2 pk = {pk_bf16(p0,p1), pk_bf16(p2,p3)};
      *(u32x2*)(pl + li*64 + (((4*mf+g) ^ swp2)*4)) = pk;
    }
    __builtin_amdgcn_s_setprio(1);
    #pragma unroll
    for (int s=0; s<2; s++){
      bf16x8 pb = *(const bf16x8*)(pl + li*64 + (((8*s+2*g) ^ swp2)*4));
      o4[c] = MFMA16(ones, pb, o4[c]);
      #pragma unroll
      for (int mf=0; mf<4; mf++)
        o[mf][c] = MFMA16(av[s][mf], pb, o[mf][c]);
    }
    __builtin_amdgcn_s_setprio(0);
  }
  __builtin_amdgcn_s_barrier();                            // B: done reading tile t
}

__global__ __launch_bounds__(256, 2) void k_attn(
    const uint16_t* __restrict__ qg, const uint16_t* __restrict__ kg,
    const uint16_t* __restrict__ vg, const float* __restrict__ biast,
    uint16_t* __restrict__ outp)
{
  __shared__ __align__(16) uint16_t kt[2][64*64];  // K tile [kv][d], 16B-chunk ^= row&7 (16KB)
  __shared__ __align__(16) uint16_t vt[2][64*64];  // V^T tile [d][kv], same swizzle   (16KB)
  __shared__ __align__(16) uint16_t pt[4][16*64];  // per-wave P^T [16q][64kv], reused  (8KB)
  const int tid = threadIdx.x;
  const int lane = tid & 63, w = tid >> 6;         // 4 waves
  const int g = lane >> 4, li = lane & 15;
  const int bh = blockIdx.y, h = bh & 15, b_ = bh >> 4;
  const int qw = blockIdx.x*128 + w*32;            // wave's q base (32 rows)

  bf16x8 qf[2][2];
  #pragma unroll
  for (int c=0;c<2;c++){
    const uint16_t* qp = qg + ((size_t)bh*2048 + qw + c*16 + li)*64 + g*8;
    qf[c][0] = *(const bf16x8*)(qp);
    qf[c][1] = *(const bf16x8*)(qp + 32);
  }
  bf16x8 ones = (bf16x8)(short)0;                  // A-frag: row 0 = 1.0, rows 1-15 = 0
  if (li == 0){ const short v = (short)0x3F80; ones = (bf16x8){v,v,v,v,v,v,v,v}; }

  f32x4 o[4][2] = {};
  f32x4 o4[2] = {};
  float mrun0 = -__builtin_inff(), mrun1 = -__builtin_inff();

  const uint16_t* kbase = kg + (size_t)bh*(2048*64);
  const uint16_t* vbase = vg + (size_t)bh*(64*2048);
  const int srow = tid >> 3;                       // 0..31
  const int scg  = (tid & 7) ^ (srow & 7);
  const float* bb = biast + h*4096 + 2047 - qw;    // + kv - (c*16+li)
  uint16_t* pl = &pt[w][0];

  // prologue: stage tile 0
  gload16(kbase + (size_t)srow*64 + scg*8,         &kt[0][tid*8]);
  gload16(kbase + (size_t)(srow+32)*64 + scg*8,    &kt[0][2048 + tid*8]);
  gload16(vbase + (size_t)srow*2048 + scg*8,       &vt[0][tid*8]);
  gload16(vbase + (size_t)(srow+32)*2048 + scg*8,  &vt[0][2048 + tid*8]);

  for (int tt = 0; tt < 32; tt += 2){
    attn_tile(tt,   false,    tid, g, li, srow, scg, kbase, vbase, bb,
              &kt[0][0], &kt[1][0], &vt[0][0], &vt[1][0], pl,
              qf, ones, o, o4, mrun0, mrun1);
    attn_tile(tt+1, tt == 30, tid, g, li, srow, scg, kbase, vbase, bb,
              &kt[1][0], &kt[0][0], &vt[1][0], &vt[0][0], pl,
              qf, ones, o, o4, mrun0, mrun1);
  }

  // row sums in o4[c] reg 0 of g=0 lanes; broadcast; write normalized O
  const float ls0 = __shfl(o4[0][0], li);
  const float ls1 = __shfl(o4[1][0], li);
  const float inv0 = 1.0f / ls0, inv1 = 1.0f / ls1;
  #pragma unroll
  for (int c=0;c<2;c++){
    const float inv = c ? inv1 : inv0;
    const size_t token = (size_t)b_*2048 + qw + c*16 + li;
    #pragma unroll
    for (int mf=0; mf<4; mf++){
      u32x2 pk = {pk_bf16(o[mf][c][0]*inv, o[mf][c][1]*inv),
                  pk_bf16(o[mf][c][2]*inv, o[mf][c][3]*inv)};
      *(u32x2*)(outp + token*1024 + h*64 + mf*16 + g*4) = pk;
    }
  }
}

// ---------- launch ----------
extern "C" void kernel_launch(void* const* d_in, const int* in_sizes, int n_in,
                              void* d_out, int out_size, void* d_ws, size_t ws_size,
                              hipStream_t stream)
{
  const float* x      = (const float*)d_in[0];
  const float* qkv_w  = (const float*)d_in[1];
  const float* qkv_b  = (const float*)d_in[2];
  const float* proj_w = (const float*)d_in[3];
  const float* proj_b = (const float*)d_in[4];
  const float* btab   = (const float*)d_in[5];
  float* out = (float*)d_out;

  char* p = (char*)d_ws;
  uint16_t* x_bf    = (uint16_t*)(p);
  uint16_t* qkv_wt  = (uint16_t*)(p + 8388608);
  uint16_t* proj_wt = (uint16_t*)(p + 14680064);
  uint16_t* q_buf   = (uint16_t*)(p + 16777216);   // (b,h,l,d) bf16, prescaled
  uint16_t* k_buf   = (uint16_t*)(p + 25165824);   // (b,h,l,d) bf16
  uint16_t* vt_buf  = (uint16_t*)(p + 33554432);   // (b,h,d,l) bf16
  uint16_t* ao_buf  = (uint16_t*)(p + 41943040);   // attn out (tokens x 1024) bf16
  float*    bias_t  = (float*)   (p + 50331648);   // 16 x 4096 f32, *log2e

  k_prep <<<dim3(5376), dim3(256), 0, stream>>>(x, x_bf, btab, bias_t,
                                                qkv_w, qkv_wt, proj_w, proj_wt);

  k_gemm  <<<dim3(24,64), dim3(256), 0, stream>>>(x_bf, qkv_wt, qkv_b, q_buf, k_buf, vt_buf);
  k_attn  <<<dim3(16,32), dim3(256), 0, stream>>>(q_buf, k_buf, vt_buf, bias_t, ao_buf);
  k_gemm2 <<<dim3(16,32), dim3(256), 0, stream>>>(ao_buf, proj_wt, proj_b, out);
}